// Round 9
// baseline (465.768 us; speedup 1.0000x reference)
//
#include <hip/hip_runtime.h>
#include <math.h>

#define C_DIM 4
#define T_DIM 4096
#define D_DIM 1024
#define E_DIM 16
#define CAP   320
#define CT    (C_DIM * T_DIM)               // 16384 tokens
#define OUT_ONE ((size_t)CT * E_DIM * CAP)  // 83,886,080 elements per big output

#define NBLOCKS 1024                         // 16 tokens per block (4 per wave)
#define N4      ((2 * OUT_ONE) / 4)          // 41,943,040 float4 to zero
#define F4_PER_BLOCK (N4 / NBLOCKS)          // 40960 float4 per block (640KB)
#define FILL_ITERS (F4_PER_BLOCK / 256)      // 160 store iterations per thread
#define FILL_PER_CHUNK (FILL_ITERS / 4)      // 40 per router r-chunk

// compile-time 6-bit bit-reverse (flatten permutation for the butterfly reduce)
__host__ __device__ constexpr int bitrev6(int i) {
    return ((i & 1) << 5) | ((i & 2) << 3) | ((i & 4) << 1)
         | ((i & 8) >> 1) | ((i & 16) >> 3) | ((i & 32) >> 5);
}

// ws layout (bytes):
//   0      : auxpart f32[64]   (per-(c,e) softmax prob sums) - zeroed each call
//   256    : counts  i32[64]   (per-(c,e) argmax histogram)  - zeroed each call
//   512    : gate    f32[CT]
//   66048  : index   i32[CT]

// ---------------------------------------------------------------------------
// Fused kernel, FINE-GRAINED INTERLEAVE: per r-chunk every wave issues its
// router loads, then 40 independent fill-store iterations (in flight while
// the FMAs wait on the loads), then the dot-product FMAs. Read and write
// streams stay continuously mixed — the regime where the memory system
// sustains ~6.3 TB/s (m13 copy). Butterfly reduce + wave-parallel softmax
// epilogue unchanged from R8. launch_bounds(256,4) pins VGPR<=128 so all
// 1024 blocks (4/CU, 16 waves) are co-resident — no tail round.
// ---------------------------------------------------------------------------
__global__ __launch_bounds__(256, 4) void fused_router_fill_kernel(
    const float* __restrict__ in, const float* __restrict__ w,
    const float* __restrict__ noise, float* __restrict__ gate,
    int* __restrict__ index, float* __restrict__ auxpart,
    int* __restrict__ counts, float4* __restrict__ out4)
{
    __shared__ float psum[E_DIM];
    __shared__ int   hcnt[E_DIM];
    const int tid = threadIdx.x;
    if (tid < E_DIM) { psum[tid] = 0.0f; hcnt[tid] = 0; }
    __syncthreads();

    const int wave = tid >> 6;
    const int lane = tid & 63;
    const int g0   = blockIdx.x * 16 + wave * 4;   // 4 tokens per wave

    const float4 z = make_float4(0.f, 0.f, 0.f, 0.f);
    float4* dst = out4 + (size_t)blockIdx.x * F4_PER_BLOCK;

    float val[64];
    #pragma unroll
    for (int i = 0; i < 64; ++i) val[i] = 0.0f;

    #pragma unroll
    for (int r = 0; r < 4; ++r) {
        const int d0 = r * 256 + lane * 4;
        // (1) issue router loads
        float4 x[4];
        #pragma unroll
        for (int tk = 0; tk < 4; ++tk) {
            const float4 a = *(const float4*)(in    + (size_t)(g0 + tk) * D_DIM + d0);
            const float4 n = *(const float4*)(noise + (size_t)(g0 + tk) * D_DIM + d0);
            x[tk] = make_float4(a.x * n.x, a.y * n.y, a.z * n.z, a.w * n.w);
        }
        // (2) issue this chunk's independent fill stores (fly during FMA stall)
        #pragma unroll 8
        for (int i = r * FILL_PER_CHUNK; i < (r + 1) * FILL_PER_CHUNK; ++i)
            dst[(size_t)i * 256 + tid] = z;
        // (3) dot-product FMAs (wait on loads; stores still in flight)
        #pragma unroll
        for (int e = 0; e < 16; ++e) {
            const float4 wv = *(const float4*)(w + e * D_DIM + d0);
            #pragma unroll
            for (int tk = 0; tk < 4; ++tk) {
                val[bitrev6(tk * 16 + e)] += x[tk].x * wv.x + x[tk].y * wv.y
                                           + x[tk].z * wv.z + x[tk].w * wv.w;
            }
        }
    }

    // Butterfly transpose-reduce: 63 shuffles; lane l ends with the full dot
    // for flattened idx l (bitrev6 flatten compensates the halving order).
    #pragma unroll
    for (int m = 0; m < 6; ++m) {
        const int half = 32 >> m;
        const int bit  = (lane >> m) & 1;
        #pragma unroll
        for (int j = 0; j < half; ++j) {
            const float send = bit ? val[j] : val[j + half];
            const float recv = __shfl_xor(send, 1 << m, 64);
            val[j] = (bit ? val[j + half] : val[j]) + recv;
        }
    }

    const int tk = lane >> 4;
    const int e  = lane & 15;
    const float logit = val[0];
    const int g = g0 + tk;

    // 16-lane-group max with first-index tie-break
    float mv = logit; int am = e;
    #pragma unroll
    for (int msk = 1; msk <= 8; msk <<= 1) {
        const float ov = __shfl_xor(mv, msk, 64);
        const int   oe = __shfl_xor(am, msk, 64);
        if (ov > mv || (ov == mv && oe < am)) { mv = ov; am = oe; }
    }

    const float p = __expf(logit - mv);
    float s = p;
    #pragma unroll
    for (int msk = 1; msk <= 8; msk <<= 1)
        s += __shfl_xor(s, msk, 64);

    const float inv = 1.0f / s;
    if (e == am) {                       // exactly one lane per token
        gate[g]  = inv;                  // probs[argmax] = exp(0)/s
        index[g] = am;
        atomicAdd(&hcnt[am], 1);
    }

    // per-e total of normalized probs over this wave's 4 tokens: after
    // xor-16/32 all lanes hold the wave total; lanes 0..15 add once.
    float pn = p * inv;
    pn += __shfl_xor(pn, 16, 64);
    pn += __shfl_xor(pn, 32, 64);
    if (lane < 16)
        atomicAdd(&psum[e], pn);

    __syncthreads();
    if (tid < 16) {
        const int c = blockIdx.x >> 8;   // 256 blocks per c
        atomicAdd(&auxpart[c * 16 + tid], psum[tid]);
        atomicAdd(&counts [c * 16 + tid], hcnt[tid]);
    }
}

// ---------------------------------------------------------------------------
// Finalize: <=64 nonzeros (torch scatter semantics: only tokens tp<16, e=0
// slice). Rank within expert 0 computed from the first 16 indices (<=16<CAP).
// ---------------------------------------------------------------------------
__global__ __launch_bounds__(64) void finalize_kernel(
    const float* __restrict__ gate, const int* __restrict__ index,
    const int* __restrict__ counts, const float* __restrict__ auxpart,
    float* __restrict__ out)
{
    const int id = threadIdx.x;          // 0..63
    const int c  = id >> 4;
    const int tp = id & 15;
    const int cnt = counts[id];

    float term = ((float)cnt * (1.0f / T_DIM)) * (auxpart[id] * (1.0f / T_DIM));

    if (cnt > 0) {                        // expert value tp appears as an argmax
        const int g     = c * T_DIM + tp;
        const int myidx = index[g];
        int s = 0;
        if (myidx == 0) {                 // 1-based rank within expert 0 among tokens 0..tp
            int r = 0;
            for (int t = 0; t <= tp; ++t)
                r += (index[c * T_DIM + t] == 0);
            s = r;
        }
        const size_t off = ((size_t)g * E_DIM + 0) * CAP + (size_t)s;
        out[off]            = 1.0f;       // dispatch
        out[OUT_ONE + off]  = gate[g];    // combine
    }

    #pragma unroll
    for (int off = 32; off; off >>= 1)
        term += __shfl_down(term, off, 64);
    if (id == 0)
        out[2 * OUT_ONE] = 16.0f * term;  // aux_loss = E * sum(density1*proxy)
}

extern "C" void kernel_launch(void* const* d_in, const int* in_sizes, int n_in,
                              void* d_out, int out_size, void* d_ws, size_t ws_size,
                              hipStream_t stream) {
    const float* in    = (const float*)d_in[0];
    const float* w     = (const float*)d_in[1];
    const float* noise = (const float*)d_in[2];
    float* out = (float*)d_out;

    char* ws = (char*)d_ws;
    float* auxpart = (float*)(ws);
    int*   counts  = (int*)(ws + 256);
    float* gate    = (float*)(ws + 512);
    int*   index   = (int*)(ws + 512 + 65536);

    (void)hipMemsetAsync(ws, 0, 512, stream);

    fused_router_fill_kernel<<<dim3(NBLOCKS), dim3(256), 0, stream>>>(
        in, w, noise, gate, index, auxpart, counts, (float4*)out);
    finalize_kernel<<<dim3(1), dim3(64), 0, stream>>>(gate, index, counts, auxpart, out);
}

// Round 10
// 260.803 us; speedup vs baseline: 1.7859x; 1.7859x over previous
//
#include <hip/hip_runtime.h>
#include <math.h>

#define C_DIM 4
#define T_DIM 4096
#define D_DIM 1024
#define E_DIM 16
#define CAP   320
#define CT    (C_DIM * T_DIM)               // 16384 tokens
#define OUT_ONE ((size_t)CT * E_DIM * CAP)  // 83,886,080 elements per big output

#define NBLOCKS 1024                         // 16 tokens per block (4 per wave)
#define N4      ((2 * OUT_ONE) / 4)          // 41,943,040 float4 to zero
#define F4_PER_BLOCK (N4 / NBLOCKS)          // 40960 float4 per block (640KB)
#define FILL_ITERS (F4_PER_BLOCK / 256)      // 160 store iterations per thread
#define FILL_PER_CHUNK (FILL_ITERS / 4)      // 40 per router r-chunk

// compile-time 6-bit bit-reverse (flatten permutation for the butterfly reduce)
__host__ __device__ constexpr int bitrev6(int i) {
    return ((i & 1) << 5) | ((i & 2) << 3) | ((i & 4) << 1)
         | ((i & 8) >> 1) | ((i & 16) >> 3) | ((i & 32) >> 5);
}

// ws layout (bytes):
//   0      : auxpart f32[64]   (per-(c,e) softmax prob sums) - zeroed each call
//   256    : counts  i32[64]   (per-(c,e) argmax histogram)  - zeroed each call
//   512    : gate    f32[CT]
//   66048  : index   i32[CT]

// ---------------------------------------------------------------------------
// Fused kernel, fine-grained interleave (R9 structure) WITHOUT the VGPR
// clamp: R9's __launch_bounds__(256,4) forced VGPR=64 and spilled val[64] to
// scratch (WRITE_SIZE 671->1030 MB, FETCH 134->244 MB, 474us). Compiler-chosen
// allocation keeps val[64] in registers (R8 proved it fits at default).
// Per r-chunk: issue router loads -> issue 40 independent fill stores (fly
// while FMAs wait on loads) -> FMAs. Butterfly reduce + wave-parallel softmax
// epilogue unchanged from R8.
// ---------------------------------------------------------------------------
__global__ __launch_bounds__(256) void fused_router_fill_kernel(
    const float* __restrict__ in, const float* __restrict__ w,
    const float* __restrict__ noise, float* __restrict__ gate,
    int* __restrict__ index, float* __restrict__ auxpart,
    int* __restrict__ counts, float4* __restrict__ out4)
{
    __shared__ float psum[E_DIM];
    __shared__ int   hcnt[E_DIM];
    const int tid = threadIdx.x;
    if (tid < E_DIM) { psum[tid] = 0.0f; hcnt[tid] = 0; }
    __syncthreads();

    const int wave = tid >> 6;
    const int lane = tid & 63;
    const int g0   = blockIdx.x * 16 + wave * 4;   // 4 tokens per wave

    const float4 z = make_float4(0.f, 0.f, 0.f, 0.f);
    float4* dst = out4 + (size_t)blockIdx.x * F4_PER_BLOCK;

    float val[64];
    #pragma unroll
    for (int i = 0; i < 64; ++i) val[i] = 0.0f;

    #pragma unroll
    for (int r = 0; r < 4; ++r) {
        const int d0 = r * 256 + lane * 4;
        // (1) issue router loads
        float4 x[4];
        #pragma unroll
        for (int tk = 0; tk < 4; ++tk) {
            const float4 a = *(const float4*)(in    + (size_t)(g0 + tk) * D_DIM + d0);
            const float4 n = *(const float4*)(noise + (size_t)(g0 + tk) * D_DIM + d0);
            x[tk] = make_float4(a.x * n.x, a.y * n.y, a.z * n.z, a.w * n.w);
        }
        // (2) issue this chunk's independent fill stores (fly during FMA stall)
        #pragma unroll 8
        for (int i = r * FILL_PER_CHUNK; i < (r + 1) * FILL_PER_CHUNK; ++i)
            dst[(size_t)i * 256 + tid] = z;
        // (3) dot-product FMAs (wait on loads; stores still in flight)
        #pragma unroll
        for (int e = 0; e < 16; ++e) {
            const float4 wv = *(const float4*)(w + e * D_DIM + d0);
            #pragma unroll
            for (int tk = 0; tk < 4; ++tk) {
                val[bitrev6(tk * 16 + e)] += x[tk].x * wv.x + x[tk].y * wv.y
                                           + x[tk].z * wv.z + x[tk].w * wv.w;
            }
        }
    }

    // Butterfly transpose-reduce: 63 shuffles; lane l ends with the full dot
    // for flattened idx l (bitrev6 flatten compensates the halving order).
    #pragma unroll
    for (int m = 0; m < 6; ++m) {
        const int half = 32 >> m;
        const int bit  = (lane >> m) & 1;
        #pragma unroll
        for (int j = 0; j < half; ++j) {
            const float send = bit ? val[j] : val[j + half];
            const float recv = __shfl_xor(send, 1 << m, 64);
            val[j] = (bit ? val[j + half] : val[j]) + recv;
        }
    }

    const int tk = lane >> 4;
    const int e  = lane & 15;
    const float logit = val[0];
    const int g = g0 + tk;

    // 16-lane-group max with first-index tie-break
    float mv = logit; int am = e;
    #pragma unroll
    for (int msk = 1; msk <= 8; msk <<= 1) {
        const float ov = __shfl_xor(mv, msk, 64);
        const int   oe = __shfl_xor(am, msk, 64);
        if (ov > mv || (ov == mv && oe < am)) { mv = ov; am = oe; }
    }

    const float p = __expf(logit - mv);
    float s = p;
    #pragma unroll
    for (int msk = 1; msk <= 8; msk <<= 1)
        s += __shfl_xor(s, msk, 64);

    const float inv = 1.0f / s;
    if (e == am) {                       // exactly one lane per token
        gate[g]  = inv;                  // probs[argmax] = exp(0)/s
        index[g] = am;
        atomicAdd(&hcnt[am], 1);
    }

    // per-e total of normalized probs over this wave's 4 tokens: after
    // xor-16/32 all lanes hold the wave total; lanes 0..15 add once.
    float pn = p * inv;
    pn += __shfl_xor(pn, 16, 64);
    pn += __shfl_xor(pn, 32, 64);
    if (lane < 16)
        atomicAdd(&psum[e], pn);

    __syncthreads();
    if (tid < 16) {
        const int c = blockIdx.x >> 8;   // 256 blocks per c
        atomicAdd(&auxpart[c * 16 + tid], psum[tid]);
        atomicAdd(&counts [c * 16 + tid], hcnt[tid]);
    }
}

// ---------------------------------------------------------------------------
// Finalize: <=64 nonzeros (torch scatter semantics: only tokens tp<16, e=0
// slice). Rank within expert 0 computed from the first 16 indices (<=16<CAP).
// ---------------------------------------------------------------------------
__global__ __launch_bounds__(64) void finalize_kernel(
    const float* __restrict__ gate, const int* __restrict__ index,
    const int* __restrict__ counts, const float* __restrict__ auxpart,
    float* __restrict__ out)
{
    const int id = threadIdx.x;          // 0..63
    const int c  = id >> 4;
    const int tp = id & 15;
    const int cnt = counts[id];

    float term = ((float)cnt * (1.0f / T_DIM)) * (auxpart[id] * (1.0f / T_DIM));

    if (cnt > 0) {                        // expert value tp appears as an argmax
        const int g     = c * T_DIM + tp;
        const int myidx = index[g];
        int s = 0;
        if (myidx == 0) {                 // 1-based rank within expert 0 among tokens 0..tp
            int r = 0;
            for (int t = 0; t <= tp; ++t)
                r += (index[c * T_DIM + t] == 0);
            s = r;
        }
        const size_t off = ((size_t)g * E_DIM + 0) * CAP + (size_t)s;
        out[off]            = 1.0f;       // dispatch
        out[OUT_ONE + off]  = gate[g];    // combine
    }

    #pragma unroll
    for (int off = 32; off; off >>= 1)
        term += __shfl_down(term, off, 64);
    if (id == 0)
        out[2 * OUT_ONE] = 16.0f * term;  // aux_loss = E * sum(density1*proxy)
}

extern "C" void kernel_launch(void* const* d_in, const int* in_sizes, int n_in,
                              void* d_out, int out_size, void* d_ws, size_t ws_size,
                              hipStream_t stream) {
    const float* in    = (const float*)d_in[0];
    const float* w     = (const float*)d_in[1];
    const float* noise = (const float*)d_in[2];
    float* out = (float*)d_out;

    char* ws = (char*)d_ws;
    float* auxpart = (float*)(ws);
    int*   counts  = (int*)(ws + 256);
    float* gate    = (float*)(ws + 512);
    int*   index   = (int*)(ws + 512 + 65536);

    (void)hipMemsetAsync(ws, 0, 512, stream);

    fused_router_fill_kernel<<<dim3(NBLOCKS), dim3(256), 0, stream>>>(
        in, w, noise, gate, index, auxpart, counts, (float4*)out);
    finalize_kernel<<<dim3(1), dim3(64), 0, stream>>>(gate, index, counts, auxpart, out);
}

// Round 11
// 194.150 us; speedup vs baseline: 2.3990x; 1.3433x over previous
//
#include <hip/hip_runtime.h>
#include <math.h>

#define C_DIM 4
#define T_DIM 4096
#define D_DIM 1024
#define E_DIM 16
#define CAP   320
#define CT    (C_DIM * T_DIM)               // 16384 tokens
#define OUT_ONE ((size_t)CT * E_DIM * CAP)  // 83,886,080 elements per big output

#define NBLOCKS 4096                         // 4 tokens per block (1 per wave)
#define N4      ((2 * OUT_ONE) / 4)          // 41,943,040 float4 to zero
#define F4_PER_BLOCK (N4 / NBLOCKS)          // 10240 float4 per block (160KB)

// compile-time 4-bit bit-reverse (flatten permutation for the butterfly reduce)
__host__ __device__ constexpr int bitrev4(int i) {
    return ((i & 1) << 3) | ((i & 2) << 1) | ((i & 4) >> 1) | ((i & 8) >> 3);
}

// ws layout (bytes):
//   0      : auxpart f32[64]   (per-(c,e) softmax prob sums) - zeroed each call
//   256    : counts  i32[64]   (per-(c,e) argmax histogram)  - zeroed each call
//   512    : gate    f32[CT]
//   66048  : index   i32[CT]

// ---------------------------------------------------------------------------
// Fused kernel, FINE DECOMPOSITION: 4096 blocks, 1 token per wave.
//  - val[16] accumulators (vs R8's val[64]): ~3x less VGPR pressure, no spill.
//  - 8 blocks/CU resident -> 32 waves/CU (matches the 6.8 TB/s rocclr fill's
//    occupancy), 2 scheduling rounds.
//  - stagger parity (R7/R8-proven): odd blocks fill first, even route first;
//    fill slices are 160KB so read/write epochs interleave 4x finer than R8.
//  - butterfly reduce: 4 levels within 16-lane groups (15 shuffles) + xor16/32
//    cross-group combine (2 shuffles); lane l holds the token's logit for
//    expert e=l&15 (bitrev4 flatten compensates halving order).
// ---------------------------------------------------------------------------
__device__ __forceinline__ void do_router(
    const float* __restrict__ in, const float* __restrict__ w,
    const float* __restrict__ noise, float* __restrict__ gate,
    int* __restrict__ index, float* psum, int* hcnt)
{
    const int tid  = threadIdx.x;
    const int wave = tid >> 6;
    const int lane = tid & 63;
    const int g    = blockIdx.x * 4 + wave;        // this wave's token

    float val[16];
    #pragma unroll
    for (int i = 0; i < 16; ++i) val[i] = 0.0f;

    #pragma unroll
    for (int r = 0; r < 4; ++r) {
        const int d0 = r * 256 + lane * 4;
        const float4 a = *(const float4*)(in    + (size_t)g * D_DIM + d0);
        const float4 n = *(const float4*)(noise + (size_t)g * D_DIM + d0);
        const float4 x = make_float4(a.x * n.x, a.y * n.y, a.z * n.z, a.w * n.w);
        #pragma unroll
        for (int e = 0; e < 16; ++e) {
            const float4 wv = *(const float4*)(w + e * D_DIM + d0);
            val[bitrev4(e)] += x.x * wv.x + x.y * wv.y + x.z * wv.z + x.w * wv.w;
        }
    }

    // butterfly transpose-reduce within 16-lane groups: 4 levels, 15 shuffles
    #pragma unroll
    for (int m = 0; m < 4; ++m) {
        const int half = 8 >> m;
        const int bit  = (lane >> m) & 1;
        #pragma unroll
        for (int j = 0; j < half; ++j) {
            const float send = bit ? val[j] : val[j + half];
            const float recv = __shfl_xor(send, 1 << m, 64);
            val[j] = (bit ? val[j + half] : val[j]) + recv;
        }
    }
    // cross-group combine: sum the 4 16-lane-group partials
    float logit = val[0];
    logit += __shfl_xor(logit, 16, 64);
    logit += __shfl_xor(logit, 32, 64);
    // now lane l holds the complete logit for expert e = l&15

    const int e = lane & 15;

    // 16-lane-group max with first-index tie-break
    float mv = logit; int am = e;
    #pragma unroll
    for (int msk = 1; msk <= 8; msk <<= 1) {
        const float ov = __shfl_xor(mv, msk, 64);
        const int   oe = __shfl_xor(am, msk, 64);
        if (ov > mv || (ov == mv && oe < am)) { mv = ov; am = oe; }
    }

    const float p = __expf(logit - mv);
    float s = p;
    #pragma unroll
    for (int msk = 1; msk <= 8; msk <<= 1)
        s += __shfl_xor(s, msk, 64);

    const float inv = 1.0f / s;
    if (lane < 16 && e == am) {          // exactly one lane per token
        gate[g]  = inv;                  // probs[argmax] = exp(0)/s
        index[g] = am;
        atomicAdd(&hcnt[am], 1);
    }
    if (lane < 16)
        atomicAdd(&psum[e], p * inv);    // one add per (wave, e)
}

__device__ __forceinline__ void do_fill(float4* __restrict__ out4)
{
    const float4 z = make_float4(0.f, 0.f, 0.f, 0.f);
    float4* dst = out4 + (size_t)blockIdx.x * F4_PER_BLOCK;
    #pragma unroll 8
    for (int i = threadIdx.x; i < F4_PER_BLOCK; i += 256)
        dst[i] = z;
}

__global__ __launch_bounds__(256) void fused_router_fill_kernel(
    const float* __restrict__ in, const float* __restrict__ w,
    const float* __restrict__ noise, float* __restrict__ gate,
    int* __restrict__ index, float* __restrict__ auxpart,
    int* __restrict__ counts, float4* __restrict__ out4)
{
    __shared__ float psum[E_DIM];
    __shared__ int   hcnt[E_DIM];
    const int tid = threadIdx.x;
    if (tid < E_DIM) { psum[tid] = 0.0f; hcnt[tid] = 0; }
    __syncthreads();

    if (blockIdx.x & 1) {
        do_fill(out4);
        do_router(in, w, noise, gate, index, psum, hcnt);
    } else {
        do_router(in, w, noise, gate, index, psum, hcnt);
        do_fill(out4);
    }

    __syncthreads();
    if (tid < 16) {
        const int c = blockIdx.x >> 10;  // 1024 blocks per c
        atomicAdd(&auxpart[c * 16 + tid], psum[tid]);
        atomicAdd(&counts [c * 16 + tid], hcnt[tid]);
    }
}

// ---------------------------------------------------------------------------
// Finalize: <=64 nonzeros (torch scatter semantics: only tokens tp<16, e=0
// slice). Rank within expert 0 computed from the first 16 indices (<=16<CAP).
// ---------------------------------------------------------------------------
__global__ __launch_bounds__(64) void finalize_kernel(
    const float* __restrict__ gate, const int* __restrict__ index,
    const int* __restrict__ counts, const float* __restrict__ auxpart,
    float* __restrict__ out)
{
    const int id = threadIdx.x;          // 0..63
    const int c  = id >> 4;
    const int tp = id & 15;
    const int cnt = counts[id];

    float term = ((float)cnt * (1.0f / T_DIM)) * (auxpart[id] * (1.0f / T_DIM));

    if (cnt > 0) {                        // expert value tp appears as an argmax
        const int g     = c * T_DIM + tp;
        const int myidx = index[g];
        int s = 0;
        if (myidx == 0) {                 // 1-based rank within expert 0 among tokens 0..tp
            int r = 0;
            for (int t = 0; t <= tp; ++t)
                r += (index[c * T_DIM + t] == 0);
            s = r;
        }
        const size_t off = ((size_t)g * E_DIM + 0) * CAP + (size_t)s;
        out[off]            = 1.0f;       // dispatch
        out[OUT_ONE + off]  = gate[g];    // combine
    }

    #pragma unroll
    for (int off = 32; off; off >>= 1)
        term += __shfl_down(term, off, 64);
    if (id == 0)
        out[2 * OUT_ONE] = 16.0f * term;  // aux_loss = E * sum(density1*proxy)
}

extern "C" void kernel_launch(void* const* d_in, const int* in_sizes, int n_in,
                              void* d_out, int out_size, void* d_ws, size_t ws_size,
                              hipStream_t stream) {
    const float* in    = (const float*)d_in[0];
    const float* w     = (const float*)d_in[1];
    const float* noise = (const float*)d_in[2];
    float* out = (float*)d_out;

    char* ws = (char*)d_ws;
    float* auxpart = (float*)(ws);
    int*   counts  = (int*)(ws + 256);
    float* gate    = (float*)(ws + 512);
    int*   index   = (int*)(ws + 512 + 65536);

    (void)hipMemsetAsync(ws, 0, 512, stream);

    fused_router_fill_kernel<<<dim3(NBLOCKS), dim3(256), 0, stream>>>(
        in, w, noise, gate, index, auxpart, counts, (float4*)out);
    finalize_kernel<<<dim3(1), dim3(64), 0, stream>>>(gate, index, counts, auxpart, out);
}

// Round 12
// 179.083 us; speedup vs baseline: 2.6008x; 1.0841x over previous
//
#include <hip/hip_runtime.h>
#include <math.h>

#define C_DIM 4
#define T_DIM 4096
#define D_DIM 1024
#define E_DIM 16
#define CAP   320
#define CT    (C_DIM * T_DIM)               // 16384 tokens
#define OUT_ONE ((size_t)CT * E_DIM * CAP)  // 83,886,080 elements per big output

#define NBLOCKS 2048                         // 8 tokens per block (2 per wave)
#define N4      ((2 * OUT_ONE) / 4)          // 41,943,040 float4 to zero
#define F4_PER_BLOCK (N4 / NBLOCKS)          // 20480 float4 per block (320KB)

// compile-time 5-bit bit-reverse (flatten permutation for the butterfly reduce)
__host__ __device__ constexpr int bitrev5(int i) {
    return ((i & 1) << 4) | ((i & 2) << 2) | (i & 4) | ((i & 8) >> 2) | ((i & 16) >> 4);
}

// ws layout (bytes):
//   0      : auxpart f32[64]   (per-(c,e) softmax prob sums) - zeroed each call
//   256    : counts  i32[64]   (per-(c,e) argmax histogram)  - zeroed each call
//   512    : gate    f32[CT]
//   66048  : index   i32[CT]

// ---------------------------------------------------------------------------
// Fused kernel, 2 TOKENS/WAVE midpoint (R8=4/wave:171, R11=1/wave:194):
//  - val[32] accumulators: ~70 VGPR (vs R8's ~120) -> more waves co-resident
//    to feed the write stream; W-amortization only 2x worse than R8.
//  - 2048 blocks, 320KB fill slices: stagger epochs 2x finer than R8.
//  - butterfly: 5 levels within 32-lane groups (31 shuffles) + xor-32 combine;
//    lane l holds the complete logit for (tk=(l>>4)&1, e=l&15), duplicated
//    across the two 32-lane halves (bitrev5 flatten compensates halving).
//  - stagger parity (R7/R8-proven): odd blocks fill first, even route first.
// ---------------------------------------------------------------------------
__device__ __forceinline__ void do_router(
    const float* __restrict__ in, const float* __restrict__ w,
    const float* __restrict__ noise, float* __restrict__ gate,
    int* __restrict__ index, float* psum, int* hcnt)
{
    const int tid  = threadIdx.x;
    const int wave = tid >> 6;
    const int lane = tid & 63;
    const int g0   = blockIdx.x * 8 + wave * 2;    // 2 tokens per wave

    float val[32];
    #pragma unroll
    for (int i = 0; i < 32; ++i) val[i] = 0.0f;

    #pragma unroll
    for (int r = 0; r < 4; ++r) {
        const int d0 = r * 256 + lane * 4;
        float4 x[2];
        #pragma unroll
        for (int tk = 0; tk < 2; ++tk) {
            const float4 a = *(const float4*)(in    + (size_t)(g0 + tk) * D_DIM + d0);
            const float4 n = *(const float4*)(noise + (size_t)(g0 + tk) * D_DIM + d0);
            x[tk] = make_float4(a.x * n.x, a.y * n.y, a.z * n.z, a.w * n.w);
        }
        #pragma unroll
        for (int e = 0; e < 16; ++e) {
            const float4 wv = *(const float4*)(w + e * D_DIM + d0);
            #pragma unroll
            for (int tk = 0; tk < 2; ++tk) {
                val[bitrev5(tk * 16 + e)] += x[tk].x * wv.x + x[tk].y * wv.y
                                           + x[tk].z * wv.z + x[tk].w * wv.w;
            }
        }
    }

    // butterfly transpose-reduce within 32-lane groups: 5 levels, 31 shuffles
    #pragma unroll
    for (int m = 0; m < 5; ++m) {
        const int half = 16 >> m;
        const int bit  = (lane >> m) & 1;
        #pragma unroll
        for (int j = 0; j < half; ++j) {
            const float send = bit ? val[j] : val[j + half];
            const float recv = __shfl_xor(send, 1 << m, 64);
            val[j] = (bit ? val[j + half] : val[j]) + recv;
        }
    }
    // cross-half combine: sum the two 32-lane-group partials
    float logit = val[0];
    logit += __shfl_xor(logit, 32, 64);
    // lane l now holds the complete logit for (tk=(l>>4)&1, e=l&15)

    const int tk = (lane >> 4) & 1;
    const int e  = lane & 15;
    const int g  = g0 + tk;

    // 16-lane-group max with first-index tie-break
    float mv = logit; int am = e;
    #pragma unroll
    for (int msk = 1; msk <= 8; msk <<= 1) {
        const float ov = __shfl_xor(mv, msk, 64);
        const int   oe = __shfl_xor(am, msk, 64);
        if (ov > mv || (ov == mv && oe < am)) { mv = ov; am = oe; }
    }

    const float p = __expf(logit - mv);
    float s = p;
    #pragma unroll
    for (int msk = 1; msk <= 8; msk <<= 1)
        s += __shfl_xor(s, msk, 64);

    const float inv = 1.0f / s;
    if (lane < 32 && e == am) {          // exactly one lane per token (tk=0:0-15, tk=1:16-31)
        gate[g]  = inv;                  // probs[argmax] = exp(0)/s
        index[g] = am;
        atomicAdd(&hcnt[am], 1);
    }

    // per-e total of normalized probs over this wave's 2 tokens: xor-16 sums
    // across tk (same e); lanes 0..15 add once.
    float pn = p * inv;
    pn += __shfl_xor(pn, 16, 64);
    if (lane < 16)
        atomicAdd(&psum[e], pn);
}

__device__ __forceinline__ void do_fill(float4* __restrict__ out4)
{
    const float4 z = make_float4(0.f, 0.f, 0.f, 0.f);
    float4* dst = out4 + (size_t)blockIdx.x * F4_PER_BLOCK;
    #pragma unroll 8
    for (int i = threadIdx.x; i < F4_PER_BLOCK; i += 256)
        dst[i] = z;
}

__global__ __launch_bounds__(256) void fused_router_fill_kernel(
    const float* __restrict__ in, const float* __restrict__ w,
    const float* __restrict__ noise, float* __restrict__ gate,
    int* __restrict__ index, float* __restrict__ auxpart,
    int* __restrict__ counts, float4* __restrict__ out4)
{
    __shared__ float psum[E_DIM];
    __shared__ int   hcnt[E_DIM];
    const int tid = threadIdx.x;
    if (tid < E_DIM) { psum[tid] = 0.0f; hcnt[tid] = 0; }
    __syncthreads();

    if (blockIdx.x & 1) {
        do_fill(out4);
        do_router(in, w, noise, gate, index, psum, hcnt);
    } else {
        do_router(in, w, noise, gate, index, psum, hcnt);
        do_fill(out4);
    }

    __syncthreads();
    if (tid < 16) {
        const int c = blockIdx.x >> 9;   // 512 blocks per c
        atomicAdd(&auxpart[c * 16 + tid], psum[tid]);
        atomicAdd(&counts [c * 16 + tid], hcnt[tid]);
    }
}

// ---------------------------------------------------------------------------
// Finalize: <=64 nonzeros (torch scatter semantics: only tokens tp<16, e=0
// slice). Rank within expert 0 computed from the first 16 indices (<=16<CAP).
// ---------------------------------------------------------------------------
__global__ __launch_bounds__(64) void finalize_kernel(
    const float* __restrict__ gate, const int* __restrict__ index,
    const int* __restrict__ counts, const float* __restrict__ auxpart,
    float* __restrict__ out)
{
    const int id = threadIdx.x;          // 0..63
    const int c  = id >> 4;
    const int tp = id & 15;
    const int cnt = counts[id];

    float term = ((float)cnt * (1.0f / T_DIM)) * (auxpart[id] * (1.0f / T_DIM));

    if (cnt > 0) {                        // expert value tp appears as an argmax
        const int g     = c * T_DIM + tp;
        const int myidx = index[g];
        int s = 0;
        if (myidx == 0) {                 // 1-based rank within expert 0 among tokens 0..tp
            int r = 0;
            for (int t = 0; t <= tp; ++t)
                r += (index[c * T_DIM + t] == 0);
            s = r;
        }
        const size_t off = ((size_t)g * E_DIM + 0) * CAP + (size_t)s;
        out[off]            = 1.0f;       // dispatch
        out[OUT_ONE + off]  = gate[g];    // combine
    }

    #pragma unroll
    for (int off = 32; off; off >>= 1)
        term += __shfl_down(term, off, 64);
    if (id == 0)
        out[2 * OUT_ONE] = 16.0f * term;  // aux_loss = E * sum(density1*proxy)
}

extern "C" void kernel_launch(void* const* d_in, const int* in_sizes, int n_in,
                              void* d_out, int out_size, void* d_ws, size_t ws_size,
                              hipStream_t stream) {
    const float* in    = (const float*)d_in[0];
    const float* w     = (const float*)d_in[1];
    const float* noise = (const float*)d_in[2];
    float* out = (float*)d_out;

    char* ws = (char*)d_ws;
    float* auxpart = (float*)(ws);
    int*   counts  = (int*)(ws + 256);
    float* gate    = (float*)(ws + 512);
    int*   index   = (int*)(ws + 512 + 65536);

    (void)hipMemsetAsync(ws, 0, 512, stream);

    fused_router_fill_kernel<<<dim3(NBLOCKS), dim3(256), 0, stream>>>(
        in, w, noise, gate, index, auxpart, counts, (float4*)out);
    finalize_kernel<<<dim3(1), dim3(64), 0, stream>>>(gate, index, counts, auxpart, out);
}